// Round 2
// baseline (295.368 us; speedup 1.0000x reference)
//
#include <hip/hip_runtime.h>
#include <math.h>

typedef __bf16 bf16;
typedef __attribute__((ext_vector_type(8))) __bf16 bf16x8;
typedef __attribute__((ext_vector_type(4))) float f32x4;

#define B_SZ 2
#define T_SZ 1024
#define DM_SZ 1024
#define H_SZ 16
#define D_SZ 64
#define L_SZ 12
#define M_ROWS (B_SZ * T_SZ)   // 2048

__device__ __forceinline__ f32x4 mfma_16x16x32(bf16x8 a, bf16x8 b, f32x4 c) {
  return __builtin_amdgcn_mfma_f32_16x16x32_bf16(a, b, c, 0, 0, 0);
}

// ---------------------------------------------------------------------------
// Tiled transpose + fp32->bf16 cast: out[n][k] = (bf16)in[k][n]. in: R x C f32.
// ---------------------------------------------------------------------------
__global__ __launch_bounds__(256) void k_transpose(const float* __restrict__ in,
                                                   bf16* __restrict__ out,
                                                   int R, int C) {
  __shared__ __align__(16) bf16 tile[64][72];
  const int tc = blockIdx.x * 64;
  const int tr = blockIdx.y * 64;
  const int t = threadIdx.x;
  const int r = t >> 2;
  const int c4 = (t & 3) << 4;
  const float* src = in + (size_t)(tr + r) * C + tc + c4;
  f32x4 f0 = *(const f32x4*)(src);
  f32x4 f1 = *(const f32x4*)(src + 4);
  f32x4 f2 = *(const f32x4*)(src + 8);
  f32x4 f3 = *(const f32x4*)(src + 12);
#pragma unroll
  for (int e = 0; e < 4; ++e) {
    tile[r][c4 + e]      = (bf16)f0[e];
    tile[r][c4 + 4 + e]  = (bf16)f1[e];
    tile[r][c4 + 8 + e]  = (bf16)f2[e];
    tile[r][c4 + 12 + e] = (bf16)f3[e];
  }
  __syncthreads();
  bf16x8 w0, w1;
#pragma unroll
  for (int e = 0; e < 8; ++e) { w0[e] = tile[c4 + e][r]; w1[e] = tile[c4 + 8 + e][r]; }
  bf16* dst = out + (size_t)(tc + r) * R + tr + c4;
  *(bf16x8*)(dst) = w0;
  *(bf16x8*)(dst + 8) = w1;
}

// ---------------------------------------------------------------------------
// GEMM: out[m][n] = sum_k A[m][k] * Wt[n][k] + bias[n], optional elu+1.
// Block tile 128(M) x 64(N), BK=64, 4 waves, each wave 32x64.
// AF32: A is fp32 (converted to bf16 while staging into LDS), else bf16.
// MODE 0: phi(v)=v>0?v+1:exp(v) -> bf16 ; MODE 1: plain -> bf16 ; MODE 2: -> f32
// ---------------------------------------------------------------------------
#define GEMM_PHI 0
#define GEMM_BF16 1
#define GEMM_F32 2

template <int MODE, bool AF32>
__global__ __launch_bounds__(256) void k_gemm(const void* __restrict__ Araw,
                                              const bf16* __restrict__ Wt,
                                              const float* __restrict__ bias,
                                              void* __restrict__ out,
                                              int M, int N, int K) {
  __shared__ __align__(16) bf16 As[128][80];
  __shared__ __align__(16) bf16 Bs[64][80];
  const int nb = blockIdx.x * 64;
  const int mb = blockIdx.y * 128;
  const int t = threadIdx.x;
  const int wv = t >> 6;
  const int lane = t & 63;
  const int l16 = lane & 15;
  const int quad = lane >> 4;
  const int m0 = wv * 32;

  const int ar = t >> 1;        // 0..127
  const int ak = (t & 1) << 5;  // 0 / 32
  const int br = t >> 2;        // 0..63
  const int bk = (t & 3) << 4;  // 0/16/32/48

  const f32x4 zero4 = {0.f, 0.f, 0.f, 0.f};
  f32x4 acc[2][4];
#pragma unroll
  for (int i = 0; i < 2; ++i)
#pragma unroll
    for (int j = 0; j < 4; ++j) acc[i][j] = zero4;

  for (int k0 = 0; k0 < K; k0 += 64) {
    bf16x8 av[4];
    if (AF32) {
      const float* apg = (const float*)Araw + (size_t)(mb + ar) * K + k0 + ak;
      f32x4 fa[8];
#pragma unroll
      for (int i = 0; i < 8; ++i) fa[i] = *(const f32x4*)(apg + i * 4);
#pragma unroll
      for (int i = 0; i < 4; ++i)
#pragma unroll
        for (int e = 0; e < 4; ++e) {
          av[i][e] = (bf16)fa[i * 2][e];
          av[i][e + 4] = (bf16)fa[i * 2 + 1][e];
        }
    } else {
      const bf16* apg = (const bf16*)Araw + (size_t)(mb + ar) * K + k0 + ak;
#pragma unroll
      for (int i = 0; i < 4; ++i) av[i] = *(const bf16x8*)(apg + i * 8);
    }
    const bf16* bpg = Wt + (size_t)(nb + br) * K + k0 + bk;
    bf16x8 b0 = *(const bf16x8*)(bpg);
    bf16x8 b1 = *(const bf16x8*)(bpg + 8);
    __syncthreads();
#pragma unroll
    for (int i = 0; i < 4; ++i) *(bf16x8*)&As[ar][ak + i * 8] = av[i];
    *(bf16x8*)&Bs[br][bk] = b0;
    *(bf16x8*)&Bs[br][bk + 8] = b1;
    __syncthreads();
#pragma unroll
    for (int ks = 0; ks < 2; ++ks) {
      bf16x8 af0 = *(const bf16x8*)&As[m0 + l16][ks * 32 + quad * 8];
      bf16x8 af1 = *(const bf16x8*)&As[m0 + 16 + l16][ks * 32 + quad * 8];
#pragma unroll
      for (int tn = 0; tn < 4; ++tn) {
        bf16x8 bfr = *(const bf16x8*)&Bs[tn * 16 + l16][ks * 32 + quad * 8];
        acc[0][tn] = mfma_16x16x32(af0, bfr, acc[0][tn]);
        acc[1][tn] = mfma_16x16x32(af1, bfr, acc[1][tn]);
      }
    }
  }
#pragma unroll
  for (int mi = 0; mi < 2; ++mi) {
#pragma unroll
    for (int tn = 0; tn < 4; ++tn) {
      const int col = nb + tn * 16 + l16;
      const float bv = bias[col];
#pragma unroll
      for (int r = 0; r < 4; ++r) {
        const int row = mb + m0 + mi * 16 + quad * 4 + r;
        float v = acc[mi][tn][r] + bv;
        if (MODE == GEMM_PHI) v = (v > 0.f) ? (v + 1.f) : __expf(v);
        if (MODE == GEMM_F32)
          ((float*)out)[(size_t)row * N + col] = v;
        else
          ((bf16*)out)[(size_t)row * N + col] = (bf16)v;
      }
    }
  }
}

// ---------------------------------------------------------------------------
// Softmax over L=12 contiguous floats per (b,t,h) row, in place.
// ---------------------------------------------------------------------------
__global__ __launch_bounds__(256) void k_softmax12(float* __restrict__ lg, int n) {
  const int idx = blockIdx.x * 256 + threadIdx.x;
  if (idx >= n) return;
  float* p = lg + (size_t)idx * L_SZ;
  float m = p[0];
#pragma unroll
  for (int l = 1; l < L_SZ; ++l) m = fmaxf(m, p[l]);
  float e[L_SZ], s = 0.f;
#pragma unroll
  for (int l = 0; l < L_SZ; ++l) { e[l] = __expf(p[l] - m); s += e[l]; }
  const float inv = 1.f / s;
#pragma unroll
  for (int l = 0; l < L_SZ; ++l) p[l] = e[l] * inv;
}

// ---------------------------------------------------------------------------
// Fenwick weighted causal linear attention.
// Grid: (T/64 query tiles, B*H). Block 256 (4 waves); wave handles 16 q-rows.
// lvl(i,j) = 31 - clz((i+1) ^ j)  (0-indexed, j<=i) -- one level per pair.
// ---------------------------------------------------------------------------
__global__ __launch_bounds__(256) void k_attn(const bf16* __restrict__ Qp,
                                              const bf16* __restrict__ Kp,
                                              const bf16* __restrict__ V,
                                              const float* __restrict__ W,
                                              bf16* __restrict__ O) {
  __shared__ __align__(16) bf16 Ks[64][80];
  __shared__ __align__(16) bf16 VT[64][80];
  __shared__ __align__(16) bf16 Pl[4][16][80];  // wave-private P tiles
  __shared__ float Ws[64 * L_SZ];

  const int it = blockIdx.x;
  const int bh = blockIdx.y;
  const int b = bh >> 4;
  const int h = bh & 15;
  const int i0 = it * 64;
  const int t = threadIdx.x;
  const int wv = t >> 6;
  const int lane = t & 63;
  const int l16 = lane & 15;
  const int quad = lane >> 4;
  const int m0 = wv * 16;

  const size_t base_bt = (size_t)b * T_SZ;

  // Q fragments for this wave's 16 rows (held all kernel)
  const bf16* qptr = Qp + (base_bt + i0 + m0 + l16) * DM_SZ + h * 64 + quad * 8;
  const bf16x8 aq0 = *(const bf16x8*)(qptr);
  const bf16x8 aq1 = *(const bf16x8*)(qptr + 32);

  // stage softmax weights for the 64 query rows: Ws[il*12 + l]
  {
    const int f = t * 3;
#pragma unroll
    for (int u = 0; u < 3; ++u) {
      const int ff = f + u;
      const int il = ff / L_SZ, l = ff % L_SZ;
      Ws[ff] = W[(base_bt + i0 + il) * (H_SZ * L_SZ) + h * L_SZ + l];
    }
  }

  const f32x4 zero4 = {0.f, 0.f, 0.f, 0.f};
  f32x4 accn[4];
#pragma unroll
  for (int tn = 0; tn < 4; ++tn) accn[tn] = zero4;
  float den[4] = {0.f, 0.f, 0.f, 0.f};

  const int sr = t >> 2;        // staging row (j local)
  const int sc = (t & 3) << 4;  // staging col (d base)

  for (int jt = 0; jt <= it; ++jt) {
    const int j0 = jt * 64;
    const bf16* kpg = Kp + (base_bt + j0 + sr) * DM_SZ + h * 64 + sc;
    bf16x8 k0v = *(const bf16x8*)(kpg);
    bf16x8 k1v = *(const bf16x8*)(kpg + 8);
    const bf16* vpg = V + (base_bt + j0 + sr) * DM_SZ + h * 64 + sc;
    bf16x8 v0v = *(const bf16x8*)(vpg);
    bf16x8 v1v = *(const bf16x8*)(vpg + 8);
    __syncthreads();  // previous iteration's LDS reads complete
    *(bf16x8*)&Ks[sr][sc] = k0v;
    *(bf16x8*)&Ks[sr][sc + 8] = k1v;
#pragma unroll
    for (int e = 0; e < 8; ++e) { VT[sc + e][sr] = v0v[e]; VT[sc + 8 + e][sr] = v1v[e]; }
    __syncthreads();

    // S = Qp * Kp^T  (16 x 64 per wave)
    f32x4 sacc[4];
#pragma unroll
    for (int tn = 0; tn < 4; ++tn) {
      sacc[tn] = zero4;
      bf16x8 bk0 = *(const bf16x8*)&Ks[tn * 16 + l16][quad * 8];
      bf16x8 bk1 = *(const bf16x8*)&Ks[tn * 16 + l16][32 + quad * 8];
      sacc[tn] = mfma_16x16x32(aq0, bk0, sacc[tn]);
      sacc[tn] = mfma_16x16x32(aq1, bk1, sacc[tn]);
    }

    // P = S * w[lvl(i,j)], causal mask; write to wave-private LDS (A-layout src)
#pragma unroll
    for (int tn = 0; tn < 4; ++tn) {
#pragma unroll
      for (int r = 0; r < 4; ++r) {
        const int il = m0 + quad * 4 + r;
        const int ig = i0 + il;
        const int jg = j0 + tn * 16 + l16;
        float p = 0.f;
        if (jg <= ig) {
          const int lvl = 31 - __clz((unsigned)((ig + 1) ^ jg));
          p = sacc[tn][r] * Ws[il * L_SZ + lvl];
        }
        den[r] += p;
        Pl[wv][quad * 4 + r][tn * 16 + l16] = (bf16)p;
      }
    }

    // num += P @ V   (A = P from LDS, B = V^T from LDS)
#pragma unroll
    for (int ks = 0; ks < 2; ++ks) {
      bf16x8 apf = *(const bf16x8*)&Pl[wv][l16][ks * 32 + quad * 8];
#pragma unroll
      for (int tn = 0; tn < 4; ++tn) {
        bf16x8 bvf = *(const bf16x8*)&VT[tn * 16 + l16][ks * 32 + quad * 8];
        accn[tn] = mfma_16x16x32(apf, bvf, accn[tn]);
      }
    }
  }

  // reduce den across the 16 column lanes (bits 0..3 of lane)
#pragma unroll
  for (int r = 0; r < 4; ++r) {
    float d = den[r];
    d += __shfl_xor(d, 1, 64);
    d += __shfl_xor(d, 2, 64);
    d += __shfl_xor(d, 4, 64);
    d += __shfl_xor(d, 8, 64);
    den[r] = fmaxf(d, 1e-6f);
  }

#pragma unroll
  for (int tn = 0; tn < 4; ++tn) {
#pragma unroll
    for (int r = 0; r < 4; ++r) {
      const int il = m0 + quad * 4 + r;
      O[(base_bt + i0 + il) * DM_SZ + h * 64 + tn * 16 + l16] =
          (bf16)(accn[tn][r] / den[r]);
    }
  }
}

// ---------------------------------------------------------------------------
extern "C" void kernel_launch(void* const* d_in, const int* in_sizes, int n_in,
                              void* d_out, int out_size, void* d_ws, size_t ws_size,
                              hipStream_t stream) {
  (void)in_sizes; (void)n_in; (void)out_size; (void)ws_size;
  const float* x  = (const float*)d_in[0];
  const float* qw = (const float*)d_in[1];
  const float* qb = (const float*)d_in[2];
  const float* kw = (const float*)d_in[3];
  const float* kb = (const float*)d_in[4];
  const float* vw = (const float*)d_in[5];
  const float* vb = (const float*)d_in[6];
  const float* lw = (const float*)d_in[7];
  const float* lb = (const float*)d_in[8];
  const float* ow = (const float*)d_in[9];
  const float* ob = (const float*)d_in[10];
  // d_in[11] = level_masks: unused — Fenwick level computed analytically:
  // lvl(i,j) = 31 - clz((i+1) ^ j), the unique level per causal (i,j) pair.

  char* ws = (char*)d_ws;
  size_t off = 0;
  auto alloc = [&](size_t bytes) -> char* {
    char* p = ws + off;
    off += (bytes + 255) & ~(size_t)255;
    return p;
  };
  bf16* qwT    = (bf16*)alloc((size_t)DM_SZ * DM_SZ * 2);
  bf16* kwT    = (bf16*)alloc((size_t)DM_SZ * DM_SZ * 2);
  bf16* vwT    = (bf16*)alloc((size_t)DM_SZ * DM_SZ * 2);
  bf16* owT    = (bf16*)alloc((size_t)DM_SZ * DM_SZ * 2);
  bf16* lwT    = (bf16*)alloc((size_t)(H_SZ * L_SZ) * DM_SZ * 2);
  bf16* Qp     = (bf16*)alloc((size_t)M_ROWS * DM_SZ * 2);
  bf16* Kpb    = (bf16*)alloc((size_t)M_ROWS * DM_SZ * 2);
  bf16* Vb     = (bf16*)alloc((size_t)M_ROWS * DM_SZ * 2);
  bf16* attn   = (bf16*)alloc((size_t)M_ROWS * DM_SZ * 2);
  float* logit = (float*)alloc((size_t)M_ROWS * H_SZ * L_SZ * 4);

  const dim3 blk(256);
  k_transpose<<<dim3(16, 16), blk, 0, stream>>>(qw, qwT, DM_SZ, DM_SZ);
  k_transpose<<<dim3(16, 16), blk, 0, stream>>>(kw, kwT, DM_SZ, DM_SZ);
  k_transpose<<<dim3(16, 16), blk, 0, stream>>>(vw, vwT, DM_SZ, DM_SZ);
  k_transpose<<<dim3(16, 16), blk, 0, stream>>>(ow, owT, DM_SZ, DM_SZ);
  k_transpose<<<dim3(3, 16), blk, 0, stream>>>(lw, lwT, DM_SZ, H_SZ * L_SZ);

  k_gemm<GEMM_PHI, true><<<dim3(16, 16), blk, 0, stream>>>(x, qwT, qb, Qp, M_ROWS, DM_SZ, DM_SZ);
  k_gemm<GEMM_PHI, true><<<dim3(16, 16), blk, 0, stream>>>(x, kwT, kb, Kpb, M_ROWS, DM_SZ, DM_SZ);
  k_gemm<GEMM_BF16, true><<<dim3(16, 16), blk, 0, stream>>>(x, vwT, vb, Vb, M_ROWS, DM_SZ, DM_SZ);
  k_gemm<GEMM_F32, true><<<dim3(3, 16), blk, 0, stream>>>(x, lwT, lb, logit, M_ROWS, H_SZ * L_SZ, DM_SZ);

  k_softmax12<<<dim3((M_ROWS * H_SZ) / 256), blk, 0, stream>>>(logit, M_ROWS * H_SZ);

  k_attn<<<dim3(T_SZ / 64, B_SZ * H_SZ), blk, 0, stream>>>(Qp, Kpb, Vb, logit, attn);

  k_gemm<GEMM_F32, false><<<dim3(16, 16), blk, 0, stream>>>(attn, owT, ob, d_out, M_ROWS, DM_SZ, DM_SZ);
}

// Round 3
// 202.017 us; speedup vs baseline: 1.4621x; 1.4621x over previous
//
#include <hip/hip_runtime.h>
#include <math.h>

typedef __bf16 bf16;
typedef __attribute__((ext_vector_type(8))) __bf16 bf16x8;
typedef __attribute__((ext_vector_type(4))) float f32x4;

#define B_SZ 2
#define T_SZ 1024
#define DM_SZ 1024
#define H_SZ 16
#define D_SZ 64
#define L_SZ 12
#define M_ROWS 2048      // B*T
#define N_FUSED 3264     // 1024(q)+1024(k)+1024(v)+192(l)

__device__ __forceinline__ f32x4 mfma_16x16x32(bf16x8 a, bf16x8 b, f32x4 c) {
  return __builtin_amdgcn_mfma_f32_16x16x32_bf16(a, b, c, 0, 0, 0);
}

// ---------------------------------------------------------------------------
// fp32 -> bf16 flat cast (x: 2048x1024)
// ---------------------------------------------------------------------------
__global__ __launch_bounds__(256) void k_cast(const float* __restrict__ in,
                                              bf16* __restrict__ out) {
  const int idx = blockIdx.x * 256 + threadIdx.x;  // per 8 elements
  const float* p = in + (size_t)idx * 8;
  f32x4 a = *(const f32x4*)p;
  f32x4 b = *(const f32x4*)(p + 4);
  bf16x8 o;
#pragma unroll
  for (int e = 0; e < 4; ++e) { o[e] = (bf16)a[e]; o[e + 4] = (bf16)b[e]; }
  *(bf16x8*)(out + (size_t)idx * 8) = o;
}

// ---------------------------------------------------------------------------
// fp32 weight transpose + cast: out[n][k] = (bf16)in[k][n]. in: R x C f32.
// grid.z selects among up to 4 (in,out) pairs.
// ---------------------------------------------------------------------------
__global__ __launch_bounds__(256) void k_transpose4(
    const float* __restrict__ in0, bf16* __restrict__ out0,
    const float* __restrict__ in1, bf16* __restrict__ out1,
    const float* __restrict__ in2, bf16* __restrict__ out2,
    const float* __restrict__ in3, bf16* __restrict__ out3, int R, int C) {
  __shared__ __align__(16) bf16 tile[64][66];
  const float* in = blockIdx.z == 0 ? in0 : blockIdx.z == 1 ? in1 : blockIdx.z == 2 ? in2 : in3;
  bf16* out = blockIdx.z == 0 ? out0 : blockIdx.z == 1 ? out1 : blockIdx.z == 2 ? out2 : out3;
  const int tc = blockIdx.x * 64;
  const int tr = blockIdx.y * 64;
  const int t = threadIdx.x;
  const int r = t >> 2;
  const int c4 = (t & 3) << 4;
  const float* src = in + (size_t)(tr + r) * C + tc + c4;
  f32x4 f0 = *(const f32x4*)(src);
  f32x4 f1 = *(const f32x4*)(src + 4);
  f32x4 f2 = *(const f32x4*)(src + 8);
  f32x4 f3 = *(const f32x4*)(src + 12);
#pragma unroll
  for (int e = 0; e < 4; ++e) {
    tile[r][c4 + e]      = (bf16)f0[e];
    tile[r][c4 + 4 + e]  = (bf16)f1[e];
    tile[r][c4 + 8 + e]  = (bf16)f2[e];
    tile[r][c4 + 12 + e] = (bf16)f3[e];
  }
  __syncthreads();
  bf16x8 w0, w1;
#pragma unroll
  for (int e = 0; e < 8; ++e) { w0[e] = tile[c4 + e][r]; w1[e] = tile[c4 + 8 + e][r]; }
  bf16* dst = out + (size_t)(tc + r) * R + tr + c4;
  *(bf16x8*)(dst) = w0;
  *(bf16x8*)(dst + 8) = w1;
}

// ---------------------------------------------------------------------------
// V transpose (bf16): V[b][t][h*64+d] -> VTg[(b*16+h)*64+d][t]
// grid (T/64, B*H)
// ---------------------------------------------------------------------------
__global__ __launch_bounds__(256) void k_vtrans(const bf16* __restrict__ V,
                                                bf16* __restrict__ VTg) {
  __shared__ __align__(16) bf16 tile[64][66];
  const int tt = blockIdx.x;
  const int bh = blockIdx.y;
  const int b = bh >> 4, h = bh & 15;
  const int t0 = tt * 64;
  const int t = threadIdx.x;
  const int r = t >> 2;
  const int c4 = (t & 3) << 4;
  const bf16* src = V + (size_t)(b * T_SZ + t0 + r) * DM_SZ + h * 64 + c4;
  bf16x8 v0 = *(const bf16x8*)(src);
  bf16x8 v1 = *(const bf16x8*)(src + 8);
#pragma unroll
  for (int e = 0; e < 8; ++e) { tile[r][c4 + e] = v0[e]; tile[r][c4 + 8 + e] = v1[e]; }
  __syncthreads();
  bf16x8 w0, w1;
#pragma unroll
  for (int e = 0; e < 8; ++e) { w0[e] = tile[c4 + e][r]; w1[e] = tile[c4 + 8 + e][r]; }
  bf16* dst = VTg + ((size_t)bh * 64 + r) * T_SZ + t0 + c4;
  *(bf16x8*)(dst) = w0;
  *(bf16x8*)(dst + 8) = w1;
}

// ---------------------------------------------------------------------------
// Fused QKVL GEMM: A (2048x1024 bf16) x Wt (3264x1024 bf16, row-major n,k).
// Block tile 128(M) x 64(N), BK=64. Epilogue by column segment:
// seg0: phi->Qp, seg1: phi->Kp, seg2: plain->V, seg3: f32 logits (stride 192).
// ---------------------------------------------------------------------------
__global__ __launch_bounds__(256) void k_gemm_qkvl(
    const bf16* __restrict__ A, const bf16* __restrict__ Wt,
    const float* __restrict__ qb, const float* __restrict__ kb,
    const float* __restrict__ vb, const float* __restrict__ lb,
    bf16* __restrict__ Qp, bf16* __restrict__ Kp, bf16* __restrict__ V,
    float* __restrict__ logit) {
  __shared__ __align__(16) bf16 As[128][80];
  __shared__ __align__(16) bf16 Bs[64][80];
  const int nb = blockIdx.x * 64;
  const int mb = blockIdx.y * 128;
  const int t = threadIdx.x;
  const int wv = t >> 6;
  const int lane = t & 63;
  const int l16 = lane & 15;
  const int quad = lane >> 4;
  const int m0 = wv * 32;

  const int ar = t >> 1;        // 0..127
  const int ak = (t & 1) << 5;  // 0/32
  const int br = t >> 2;        // 0..63
  const int bk = (t & 3) << 4;  // 0/16/32/48

  const f32x4 zero4 = {0.f, 0.f, 0.f, 0.f};
  f32x4 acc[2][4];
#pragma unroll
  for (int i = 0; i < 2; ++i)
#pragma unroll
    for (int j = 0; j < 4; ++j) acc[i][j] = zero4;

  for (int k0 = 0; k0 < DM_SZ; k0 += 64) {
    const bf16* apg = A + (size_t)(mb + ar) * DM_SZ + k0 + ak;
    bf16x8 a0 = *(const bf16x8*)(apg);
    bf16x8 a1 = *(const bf16x8*)(apg + 8);
    bf16x8 a2 = *(const bf16x8*)(apg + 16);
    bf16x8 a3 = *(const bf16x8*)(apg + 24);
    const bf16* bpg = Wt + (size_t)(nb + br) * DM_SZ + k0 + bk;
    bf16x8 b0 = *(const bf16x8*)(bpg);
    bf16x8 b1 = *(const bf16x8*)(bpg + 8);
    __syncthreads();
    *(bf16x8*)&As[ar][ak] = a0;
    *(bf16x8*)&As[ar][ak + 8] = a1;
    *(bf16x8*)&As[ar][ak + 16] = a2;
    *(bf16x8*)&As[ar][ak + 24] = a3;
    *(bf16x8*)&Bs[br][bk] = b0;
    *(bf16x8*)&Bs[br][bk + 8] = b1;
    __syncthreads();
#pragma unroll
    for (int ks = 0; ks < 2; ++ks) {
      bf16x8 af0 = *(const bf16x8*)&As[m0 + l16][ks * 32 + quad * 8];
      bf16x8 af1 = *(const bf16x8*)&As[m0 + 16 + l16][ks * 32 + quad * 8];
#pragma unroll
      for (int tn = 0; tn < 4; ++tn) {
        bf16x8 bfr = *(const bf16x8*)&Bs[tn * 16 + l16][ks * 32 + quad * 8];
        acc[0][tn] = mfma_16x16x32(af0, bfr, acc[0][tn]);
        acc[1][tn] = mfma_16x16x32(af1, bfr, acc[1][tn]);
      }
    }
  }

  const int seg = nb >> 10;  // 0..3
  const int colseg0 = nb - (seg << 10);
  const float* bias = seg == 0 ? qb : seg == 1 ? kb : seg == 2 ? vb : lb;
  bf16* outb = seg == 0 ? Qp : seg == 1 ? Kp : V;

#pragma unroll
  for (int mi = 0; mi < 2; ++mi) {
#pragma unroll
    for (int tn = 0; tn < 4; ++tn) {
      const int col = colseg0 + tn * 16 + l16;
      const float bv = bias[col];
#pragma unroll
      for (int r = 0; r < 4; ++r) {
        const int row = mb + m0 + mi * 16 + quad * 4 + r;
        float v = acc[mi][tn][r] + bv;
        if (seg == 3) {
          logit[(size_t)row * (H_SZ * L_SZ) + col] = v;
        } else {
          if (seg < 2) v = (v > 0.f) ? (v + 1.f) : __expf(v);
          outb[(size_t)row * DM_SZ + col] = (bf16)v;
        }
      }
    }
  }
}

// ---------------------------------------------------------------------------
// Softmax over L=12 contiguous floats per (b,t,h) row, in place.
// ---------------------------------------------------------------------------
__global__ __launch_bounds__(256) void k_softmax12(float* __restrict__ lg, int n) {
  const int idx = blockIdx.x * 256 + threadIdx.x;
  if (idx >= n) return;
  float* p = lg + (size_t)idx * L_SZ;
  float m = p[0];
#pragma unroll
  for (int l = 1; l < L_SZ; ++l) m = fmaxf(m, p[l]);
  float e[L_SZ], s = 0.f;
#pragma unroll
  for (int l = 0; l < L_SZ; ++l) { e[l] = __expf(p[l] - m); s += e[l]; }
  const float inv = 1.f / s;
#pragma unroll
  for (int l = 0; l < L_SZ; ++l) p[l] = e[l] * inv;
}

// ---------------------------------------------------------------------------
// Fenwick weighted causal linear attention.
// 1D grid 512 = 16 q-tiles x 32 (b,h), heavy-first balanced ordering.
// lvl(i,j) = 31 - clz((i+1) ^ j)  (0-indexed, j<=i) -- one level per pair.
// Pl uses XOR swizzle col^=((row>>2)<<4): write banks 2 lanes/bank (free).
// ---------------------------------------------------------------------------
__global__ __launch_bounds__(256) void k_attn(const bf16* __restrict__ Qp,
                                              const bf16* __restrict__ Kp,
                                              const bf16* __restrict__ VTg,
                                              const float* __restrict__ W,
                                              bf16* __restrict__ O) {
  __shared__ __align__(16) bf16 Ks[64][80];
  __shared__ __align__(16) bf16 VTs[64][80];
  __shared__ __align__(16) bf16 Pl[4][16][80];
  __shared__ float Ws[64 * L_SZ];

  const int idx = blockIdx.x;
  const int s = idx >> 5;
  const int bh = idx & 31;
  const int it = (s < 8) ? (15 - s) : (s - 8);  // first round heavy, second light
  const int b = bh >> 4;
  const int h = bh & 15;
  const int i0 = it * 64;
  const int t = threadIdx.x;
  const int wv = t >> 6;
  const int lane = t & 63;
  const int l16 = lane & 15;
  const int quad = lane >> 4;
  const int m0 = wv * 16;

  const size_t base_bt = (size_t)b * T_SZ;

  const bf16* qptr = Qp + (base_bt + i0 + m0 + l16) * DM_SZ + h * 64 + quad * 8;
  const bf16x8 aq0 = *(const bf16x8*)(qptr);
  const bf16x8 aq1 = *(const bf16x8*)(qptr + 32);

  {
    const int f = t * 3;
#pragma unroll
    for (int u = 0; u < 3; ++u) {
      const int ff = f + u;
      const int il = ff / L_SZ, l = ff % L_SZ;
      Ws[ff] = W[(base_bt + i0 + il) * (H_SZ * L_SZ) + h * L_SZ + l];
    }
  }

  const f32x4 zero4 = {0.f, 0.f, 0.f, 0.f};
  f32x4 accn[4];
#pragma unroll
  for (int tn = 0; tn < 4; ++tn) accn[tn] = zero4;
  float den[4] = {0.f, 0.f, 0.f, 0.f};

  const int sr = t >> 2;        // staging row
  const int sc = (t & 3) << 4;  // staging col base

  const bf16* vtrow = VTg + ((size_t)bh * 64 + sr) * T_SZ;

  for (int jt = 0; jt <= it; ++jt) {
    const int j0 = jt * 64;
    const bf16* kpg = Kp + (base_bt + j0 + sr) * DM_SZ + h * 64 + sc;
    bf16x8 k0v = *(const bf16x8*)(kpg);
    bf16x8 k1v = *(const bf16x8*)(kpg + 8);
    const bf16* vpg = vtrow + j0 + sc;
    bf16x8 v0v = *(const bf16x8*)(vpg);
    bf16x8 v1v = *(const bf16x8*)(vpg + 8);
    __syncthreads();
    *(bf16x8*)&Ks[sr][sc] = k0v;
    *(bf16x8*)&Ks[sr][sc + 8] = k1v;
    *(bf16x8*)&VTs[sr][sc] = v0v;
    *(bf16x8*)&VTs[sr][sc + 8] = v1v;
    __syncthreads();

    // S = Qp * Kp^T  (16 x 64 per wave)
    f32x4 sacc[4];
#pragma unroll
    for (int tn = 0; tn < 4; ++tn) {
      sacc[tn] = zero4;
      bf16x8 bk0 = *(const bf16x8*)&Ks[tn * 16 + l16][quad * 8];
      bf16x8 bk1 = *(const bf16x8*)&Ks[tn * 16 + l16][32 + quad * 8];
      sacc[tn] = mfma_16x16x32(aq0, bk0, sacc[tn]);
      sacc[tn] = mfma_16x16x32(aq1, bk1, sacc[tn]);
    }

    // P = S * w[lvl(i,j)], causal mask; swizzled wave-private LDS store
#pragma unroll
    for (int tn = 0; tn < 4; ++tn) {
#pragma unroll
      for (int r = 0; r < 4; ++r) {
        const int il = m0 + quad * 4 + r;
        const int ig = i0 + il;
        const int jg = j0 + tn * 16 + l16;
        float p = 0.f;
        if (jg <= ig) {
          const int lvl = 31 - __clz((unsigned)((ig + 1) ^ jg));
          p = sacc[tn][r] * Ws[il * L_SZ + lvl];
        }
        den[r] += p;
        Pl[wv][quad * 4 + r][(tn * 16 + l16) ^ (quad << 4)] = (bf16)p;
      }
    }

    // num += P @ V
#pragma unroll
    for (int ks = 0; ks < 2; ++ks) {
      bf16x8 apf = *(const bf16x8*)&Pl[wv][l16][(ks * 32 + quad * 8) ^ ((l16 >> 2) << 4)];
#pragma unroll
      for (int tn = 0; tn < 4; ++tn) {
        bf16x8 bvf = *(const bf16x8*)&VTs[tn * 16 + l16][ks * 32 + quad * 8];
        accn[tn] = mfma_16x16x32(apf, bvf, accn[tn]);
      }
    }
  }

#pragma unroll
  for (int r = 0; r < 4; ++r) {
    float d = den[r];
    d += __shfl_xor(d, 1, 64);
    d += __shfl_xor(d, 2, 64);
    d += __shfl_xor(d, 4, 64);
    d += __shfl_xor(d, 8, 64);
    den[r] = fmaxf(d, 1e-6f);
  }

#pragma unroll
  for (int tn = 0; tn < 4; ++tn) {
#pragma unroll
    for (int r = 0; r < 4; ++r) {
      const int il = m0 + quad * 4 + r;
      O[(base_bt + i0 + il) * DM_SZ + h * 64 + tn * 16 + l16] =
          (bf16)(accn[tn][r] / den[r]);
    }
  }
}

// ---------------------------------------------------------------------------
// Output GEMM: out[m][n] = attn[m][:] . owT[n][:] + ob[n], fp32 out.
// Block tile 64x64, 4 waves (each 16 rows x 64 cols). Grid (16, 32).
// ---------------------------------------------------------------------------
__global__ __launch_bounds__(256) void k_gemm_out(const bf16* __restrict__ A,
                                                  const bf16* __restrict__ Wt,
                                                  const float* __restrict__ bias,
                                                  float* __restrict__ out) {
  __shared__ __align__(16) bf16 As[64][80];
  __shared__ __align__(16) bf16 Bs[64][80];
  const int nb = blockIdx.x * 64;
  const int mb = blockIdx.y * 64;
  const int t = threadIdx.x;
  const int wv = t >> 6;
  const int lane = t & 63;
  const int l16 = lane & 15;
  const int quad = lane >> 4;

  const int sr = t >> 2;
  const int sc = (t & 3) << 4;

  const f32x4 zero4 = {0.f, 0.f, 0.f, 0.f};
  f32x4 acc[4];
#pragma unroll
  for (int j = 0; j < 4; ++j) acc[j] = zero4;

  for (int k0 = 0; k0 < DM_SZ; k0 += 64) {
    const bf16* apg = A + (size_t)(mb + sr) * DM_SZ + k0 + sc;
    bf16x8 a0 = *(const bf16x8*)(apg);
    bf16x8 a1 = *(const bf16x8*)(apg + 8);
    const bf16* bpg = Wt + (size_t)(nb + sr) * DM_SZ + k0 + sc;
    bf16x8 b0 = *(const bf16x8*)(bpg);
    bf16x8 b1 = *(const bf16x8*)(bpg + 8);
    __syncthreads();
    *(bf16x8*)&As[sr][sc] = a0;
    *(bf16x8*)&As[sr][sc + 8] = a1;
    *(bf16x8*)&Bs[sr][sc] = b0;
    *(bf16x8*)&Bs[sr][sc + 8] = b1;
    __syncthreads();
#pragma unroll
    for (int ks = 0; ks < 2; ++ks) {
      bf16x8 af = *(const bf16x8*)&As[wv * 16 + l16][ks * 32 + quad * 8];
#pragma unroll
      for (int tn = 0; tn < 4; ++tn) {
        bf16x8 bfr = *(const bf16x8*)&Bs[tn * 16 + l16][ks * 32 + quad * 8];
        acc[tn] = mfma_16x16x32(af, bfr, acc[tn]);
      }
    }
  }
#pragma unroll
  for (int tn = 0; tn < 4; ++tn) {
    const int col = nb + tn * 16 + l16;
    const float bv = bias[col];
#pragma unroll
    for (int r = 0; r < 4; ++r) {
      const int row = mb + wv * 16 + quad * 4 + r;
      out[(size_t)row * DM_SZ + col] = acc[tn][r] + bv;
    }
  }
}

// ---------------------------------------------------------------------------
extern "C" void kernel_launch(void* const* d_in, const int* in_sizes, int n_in,
                              void* d_out, int out_size, void* d_ws, size_t ws_size,
                              hipStream_t stream) {
  (void)in_sizes; (void)n_in; (void)out_size; (void)ws_size;
  const float* x  = (const float*)d_in[0];
  const float* qw = (const float*)d_in[1];
  const float* qb = (const float*)d_in[2];
  const float* kw = (const float*)d_in[3];
  const float* kb = (const float*)d_in[4];
  const float* vw = (const float*)d_in[5];
  const float* vb = (const float*)d_in[6];
  const float* lw = (const float*)d_in[7];
  const float* lb = (const float*)d_in[8];
  const float* ow = (const float*)d_in[9];
  const float* ob = (const float*)d_in[10];
  // d_in[11] = level_masks: unused — lvl(i,j) = 31 - clz((i+1)^j).

  char* ws = (char*)d_ws;
  size_t off = 0;
  auto alloc = [&](size_t bytes) -> char* {
    char* p = ws + off;
    off += (bytes + 255) & ~(size_t)255;
    return p;
  };
  bf16* xb     = (bf16*)alloc((size_t)M_ROWS * DM_SZ * 2);
  bf16* wqkvlT = (bf16*)alloc((size_t)N_FUSED * DM_SZ * 2);
  bf16* owT    = (bf16*)alloc((size_t)DM_SZ * DM_SZ * 2);
  bf16* Qp     = (bf16*)alloc((size_t)M_ROWS * DM_SZ * 2);
  bf16* Kpb    = (bf16*)alloc((size_t)M_ROWS * DM_SZ * 2);
  bf16* Vb     = (bf16*)alloc((size_t)M_ROWS * DM_SZ * 2);
  bf16* VTg    = (bf16*)alloc((size_t)M_ROWS * DM_SZ * 2);
  bf16* attn   = (bf16*)alloc((size_t)M_ROWS * DM_SZ * 2);
  float* logit = (float*)alloc((size_t)M_ROWS * H_SZ * L_SZ * 4);

  const dim3 blk(256);
  k_cast<<<dim3(M_ROWS * DM_SZ / 8 / 256), blk, 0, stream>>>(x, xb);
  k_transpose4<<<dim3(16, 16, 4), blk, 0, stream>>>(
      qw, wqkvlT, kw, wqkvlT + (size_t)1024 * DM_SZ, vw, wqkvlT + (size_t)2048 * DM_SZ,
      ow, owT, DM_SZ, DM_SZ);
  k_transpose4<<<dim3(3, 16, 1), blk, 0, stream>>>(
      lw, wqkvlT + (size_t)3072 * DM_SZ, lw, nullptr, lw, nullptr, lw, nullptr,
      DM_SZ, H_SZ * L_SZ);

  k_gemm_qkvl<<<dim3(N_FUSED / 64, M_ROWS / 128), blk, 0, stream>>>(
      xb, wqkvlT, qb, kb, vb, lb, Qp, Kpb, Vb, logit);

  k_softmax12<<<dim3((M_ROWS * H_SZ) / 256), blk, 0, stream>>>(logit, M_ROWS * H_SZ);
  k_vtrans<<<dim3(T_SZ / 64, B_SZ * H_SZ), blk, 0, stream>>>(Vb, VTg);

  k_attn<<<dim3((T_SZ / 64) * B_SZ * H_SZ), blk, 0, stream>>>(Qp, Kpb, VTg, logit, attn);

  k_gemm_out<<<dim3(DM_SZ / 64, M_ROWS / 64), blk, 0, stream>>>(attn, owT, ob, (float*)d_out);
}